// Round 9
// baseline (230.054 us; speedup 1.0000x reference)
//
#include <hip/hip_runtime.h>
#include <stdint.h>

// Problem: out[M=2048(size_out), N=8192(batch)] = W[K,M]^T @ X[N,K]^T
//   out[m,n] = sum_k W[k,m] * X[n,k]
#define M_DIM 2048
#define N_DIM 8192
#define K_DIM 2048

typedef _Float16 f16x8 __attribute__((ext_vector_type(8)));
typedef _Float16 f16x4 __attribute__((ext_vector_type(4)));
typedef float    f32x4 __attribute__((ext_vector_type(4)));

// ---------------- fused prep + gemm ----------------
//
// Rounds 1-8: total == gemm + 116us (constant). gemm itself is invariant at
// ~72us across 4 sync schedules and a 2.6x HBM-traffic cut (R8) — so this
// round attacks the fixed 116us: prep + launch/sync overhead. ONE kernel:
//   phase 0: each of 256 blocks converts 1/256 of X (f32->f16, coalesced)
//            and 16 W 32x32 transpose-tiles via LDS.
//   grid barrier: release fence + agent-scope atomic arrive/spin (all 256
//            blocks co-resident: 128KB LDS forces 1 block/CU, grid == #CU).
//   phase 1: R8 gemm body VERBATIM (verified 3x: 71.5us, 0 bank conflicts).
// Barrier counter lives in d_ws (+40MB), reset by hipMemsetAsync each call.
//
// gemm schedule recap (m201-style): 8 waves 2Mx4N (wave tile 128x64), BK=64.
// LDS 128KB = A-ring 4x16KB + B-ring 4x16KB half-tile slots; row-permuted
// halves; 4 quadrant phases/tile (Ph1 12 reads, Ph2 8, Ph3 4, Ph4 0, with
// af/bf register caching); 2 gld_lds staged per phase, 1.5 tiles ahead;
// ONE counted vmcnt(6) per tile; XOR swizzle chunk^=(p&7) with
// inverse-swizzled source (rule #21). XCD map: bn-major (R8; FETCH -2.6x).

__device__ __forceinline__ void load_to_lds16(const void* g, void* l) {
    __builtin_amdgcn_global_load_lds(
        (__attribute__((address_space(1))) void*)(uintptr_t)g,
        (__attribute__((address_space(3))) void*)l,
        16, 0, 0);
}

__device__ __forceinline__ void stage2(const _Float16* s0, const _Float16* s1, char* d) {
    load_to_lds16(s0, d);
    load_to_lds16(s1, d + 8192);
}

#define PH_PRE()  do { asm volatile("" ::: "memory"); \
                       __builtin_amdgcn_s_barrier(); \
                       asm volatile("s_waitcnt lgkmcnt(0)" ::: "memory"); \
                       __builtin_amdgcn_s_setprio(1); } while (0)
#define PH_POST() do { __builtin_amdgcn_s_setprio(0); \
                       __builtin_amdgcn_s_barrier(); } while (0)

template <int BUF>
__device__ __forceinline__ void tileQ(const char* lds, int pA, int pB,
                                      const _Float16* sA, const _Float16* sB,
                                      char* dAw, char* dBw, int kN, int kNN,
                                      f32x4 (&acc)[8][4]) {
    const char* A0s = lds + BUF * 32768;            // A slot (BUF, qh=0)
    const char* A1s = A0s + 16384;
    const char* B0s = lds + 65536 + BUF * 32768;    // B slot (BUF, v=0)
    const char* B1s = B0s + 16384;
    constexpr int NB = (BUF ^ 1) * 32768;
    constexpr int CB = BUF * 32768;

    f16x8 af0[4][2], af1[4][2], bf[2][2];

    // ---- Ph1: Q(qh0, v0) — 12 reads; stage B1(T+1) ----
#pragma unroll
    for (int n = 0; n < 2; ++n)
#pragma unroll
        for (int k = 0; k < 2; ++k)
            bf[n][k] = *(const f16x8*)(B0s + ((pB + n * 2048) ^ (k << 6)));
#pragma unroll
    for (int m = 0; m < 4; ++m)
#pragma unroll
        for (int k = 0; k < 2; ++k)
            af0[m][k] = *(const f16x8*)(A0s + ((pA + m * 2048) ^ (k << 6)));
    stage2(sB + (size_t)32 * K_DIM + kN, sB + (size_t)160 * K_DIM + kN, dBw + NB + 16384);
    PH_PRE();
#pragma unroll
    for (int m = 0; m < 4; ++m)
#pragma unroll
        for (int n = 0; n < 2; ++n)
#pragma unroll
            for (int k = 0; k < 2; ++k)
                acc[m][n] = __builtin_amdgcn_mfma_f32_16x16x32_f16(af0[m][k], bf[n][k], acc[m][n], 0, 0, 0);
    PH_POST();

    // ---- Ph2: Q(qh1, v0) — 8 reads (bf cached); stage A0(T+2) ----
#pragma unroll
    for (int m = 0; m < 4; ++m)
#pragma unroll
        for (int k = 0; k < 2; ++k)
            af1[m][k] = *(const f16x8*)(A1s + ((pA + m * 2048) ^ (k << 6)));
    stage2(sA + kNN, sA + (size_t)128 * K_DIM + kNN, dAw + CB);
    PH_PRE();
#pragma unroll
    for (int m = 0; m < 4; ++m)
#pragma unroll
        for (int n = 0; n < 2; ++n)
#pragma unroll
            for (int k = 0; k < 2; ++k)
                acc[4 + m][n] = __builtin_amdgcn_mfma_f32_16x16x32_f16(af1[m][k], bf[n][k], acc[4 + m][n], 0, 0, 0);
    PH_POST();

    // ---- Ph3: Q(qh1, v1) — 4 reads (af1 cached); stage B0(T+2) ----
#pragma unroll
    for (int n = 0; n < 2; ++n)
#pragma unroll
        for (int k = 0; k < 2; ++k)
            bf[n][k] = *(const f16x8*)(B1s + ((pB + n * 2048) ^ (k << 6)));
    stage2(sB + kNN, sB + (size_t)128 * K_DIM + kNN, dBw + CB);
    PH_PRE();
#pragma unroll
    for (int m = 0; m < 4; ++m)
#pragma unroll
        for (int n = 0; n < 2; ++n)
#pragma unroll
            for (int k = 0; k < 2; ++k)
                acc[4 + m][2 + n] = __builtin_amdgcn_mfma_f32_16x16x32_f16(af1[m][k], bf[n][k], acc[4 + m][2 + n], 0, 0, 0);
    PH_POST();

    // ---- Ph4: Q(qh0, v1) — 0 reads (af0+bf cached); stage A1(T+2); vmcnt(6) ----
    stage2(sA + (size_t)64 * K_DIM + kNN, sA + (size_t)192 * K_DIM + kNN, dAw + CB + 16384);
    asm volatile("s_waitcnt vmcnt(6)" ::: "memory");
    __builtin_amdgcn_s_barrier();
    __builtin_amdgcn_s_setprio(1);
#pragma unroll
    for (int m = 0; m < 4; ++m)
#pragma unroll
        for (int n = 0; n < 2; ++n)
#pragma unroll
            for (int k = 0; k < 2; ++k)
                acc[m][2 + n] = __builtin_amdgcn_mfma_f32_16x16x32_f16(af0[m][k], bf[n][k], acc[m][2 + n], 0, 0, 0);
    PH_POST();
}

__global__ __launch_bounds__(512, 2) void fused_gemm(const float* __restrict__ X,
                                                     const float* __restrict__ W,
                                                     _Float16* __restrict__ Xb,
                                                     _Float16* __restrict__ Wt,
                                                     unsigned* __restrict__ cnt,
                                                     float* __restrict__ C) {
    extern __shared__ char lds[];          // prep: 2 transpose tiles; gemm: 128KB rings

    const int tid = threadIdx.x;
    const int blk = blockIdx.x;            // 0..255

    // ================= phase 0a: X f32 -> f16 (1/256 of X per block) =================
    {
        const size_t base = (size_t)blk * 65536;
#pragma unroll 4
        for (int i = 0; i < 16; ++i) {
            const size_t e = base + (size_t)(i * 512 + tid) * 8;
            float4 a = *(const float4*)(X + e);
            float4 c4 = *(const float4*)(X + e + 4);
            f16x8 h;
            h[0] = (_Float16)a.x;  h[1] = (_Float16)a.y;  h[2] = (_Float16)a.z;  h[3] = (_Float16)a.w;
            h[4] = (_Float16)c4.x; h[5] = (_Float16)c4.y; h[6] = (_Float16)c4.z; h[7] = (_Float16)c4.w;
            *(f16x8*)(Xb + e) = h;
        }
    }

    // ================= phase 0b: W [K,M] -> Wt [M,K] (16 tiles/block, 2 at a time) ===
    {
        float* tp = (float*)lds + (tid >> 8) * (32 * 33);
        const int t2 = tid & 255;
        const int tx = t2 & 31, ty = t2 >> 5;
        const int ml = t2 >> 3, kg = (t2 & 7) * 4;
        for (int j = 0; j < 8; ++j) {
            const int tau = blk * 16 + j * 2 + (tid >> 8);
            const int m0 = (tau & 63) * 32;
            const int k0 = (tau >> 6) * 32;
            __syncthreads();               // prev iter's tile reads done
#pragma unroll
            for (int i = 0; i < 32; i += 8)
                tp[(ty + i) * 33 + tx] = W[(size_t)(k0 + ty + i) * M_DIM + m0 + tx];
            __syncthreads();
            f16x4 v;
#pragma unroll
            for (int q = 0; q < 4; ++q) v[q] = (_Float16)tp[(kg + q) * 33 + ml];
            *(f16x4*)(Wt + (size_t)(m0 + ml) * K_DIM + k0 + kg) = v;
        }
    }
    __syncthreads();

    // ================= grid barrier (256 co-resident blocks, agent scope) ============
    if (tid == 0) {
        __threadfence();                   // release prep writes (agent scope)
        __hip_atomic_fetch_add(cnt, 1u, __ATOMIC_ACQ_REL, __HIP_MEMORY_SCOPE_AGENT);
        while (__hip_atomic_load(cnt, __ATOMIC_ACQUIRE, __HIP_MEMORY_SCOPE_AGENT) < 256u) {}
        __threadfence();                   // acquire: invalidate stale L1/L2
    }
    __syncthreads();

    // ================= phase 1: gemm (R8 body, verbatim) =============================
    const int wave = tid >> 6;
    const int lane = tid & 63;
    const int lm = lane & 15, kq = lane >> 4;
    const int wm = wave >> 2, wn = wave & 3;   // 2x4 wave grid, each 128x64 of C

    // XCD map (R8, bn-major): XCD x owns bn in {4x..4x+3} x all 8 bm
    const int xcd   = blk & 7;
    const int local = blk >> 3;            // 0..31 within XCD
    const int bn = xcd * 4 + (local & 3);  // 0..31
    const int bm = local >> 2;             // 0..7

    // staging source (per-thread): slot-row q8 = tid>>3, inverse-swizzled chunk
    const int q8 = tid >> 3;                              // 0..63
    const int cg = ((tid & 7) ^ (q8 & 7)) * 8;            // f16 elems
    const _Float16* sA = Wt + (size_t)(bm * 256 + q8) * K_DIM + cg;
    const _Float16* sB = Xb + (size_t)(bn * 256 + (q8 >> 5) * 64 + (q8 & 31)) * K_DIM + cg;
    char* dAw = lds + wave * 1024;             // + buf*32768 + h*16384 (+8192 j=1)
    char* dBw = lds + 65536 + wave * 1024;

    // fragment read offsets: row p, chunk (kk*4+kq)^(p&7); p&7 == lm&7
    const int pA = (wm * 64 + lm) * 128 + (kq ^ (lm & 7)) * 16;   // + mi*2048, ^(kk<<6)
    const int pB = (wn * 32 + lm) * 128 + (kq ^ (lm & 7)) * 16;   // + ni*2048, ^(kk<<6)

    f32x4 acc[8][4] = {};

    // prologue: A0,B0,A1,B1(tile0) + A0,B0,A1(tile1) = 14 loads; vmcnt(6)
    stage2(sA,                       sA + (size_t)128 * K_DIM,       dAw);            // A0(0)
    stage2(sB,                       sB + (size_t)128 * K_DIM,       dBw);            // B0(0)
    stage2(sA + (size_t)64 * K_DIM,  sA + (size_t)192 * K_DIM,       dAw + 16384);    // A1(0)
    stage2(sB + (size_t)32 * K_DIM,  sB + (size_t)160 * K_DIM,       dBw + 16384);    // B1(0)
    stage2(sA + 64,                  sA + (size_t)128 * K_DIM + 64,  dAw + 32768);            // A0(1)
    stage2(sB + 64,                  sB + (size_t)128 * K_DIM + 64,  dBw + 32768);            // B0(1)
    stage2(sA + (size_t)64 * K_DIM + 64, sA + (size_t)192 * K_DIM + 64, dAw + 32768 + 16384); // A1(1)
    asm volatile("s_waitcnt vmcnt(6)" ::: "memory");
    __builtin_amdgcn_s_barrier();

    // main loop: 32 K-tiles; tile T in buf T&1; stages B1(T+1), A0/B0/A1(T+2)
#pragma unroll 1
    for (int t2 = 0; t2 < 16; ++t2) {
        const int T = t2 * 2;
        tileQ<0>(lds, pA, pB, sA, sB, dAw, dBw,
                 ((T + 1) & 31) * 64, ((T + 2) & 31) * 64, acc);
        tileQ<1>(lds, pA, pB, sA, sB, dAw, dBw,
                 ((T + 2) & 31) * 64, ((T + 3) & 31) * 64, acc);
    }
    asm volatile("s_waitcnt vmcnt(0)" ::: "memory");   // retire trailing DMA

    // epilogue: D row (m) = kq*4 + reg, col (n) = lm  (verified 16x16 layout)
    const int cm0 = bm * 256 + wm * 128 + kq * 4;
    const int cn0 = bn * 256 + wn * 64 + lm;
#pragma unroll
    for (int mi = 0; mi < 8; ++mi)
#pragma unroll
        for (int ni = 0; ni < 4; ++ni) {
            float* cp = C + (size_t)(cm0 + mi * 16) * N_DIM + cn0 + ni * 16;
#pragma unroll
            for (int r = 0; r < 4; ++r) cp[(size_t)r * N_DIM] = acc[mi][ni][r];
        }
}

// ---------------- fp32 fallback (only if ws too small) ----------------

__global__ __launch_bounds__(256) void gemm_f32_fallback(const float* __restrict__ X,
                                                         const float* __restrict__ W,
                                                         float* __restrict__ C) {
    __shared__ float As2[16][64];
    __shared__ float Bs2[16][64];
    const int tid = threadIdx.x;
    const int bm = blockIdx.x & 31;
    const int bn = blockIdx.x >> 5;
    const int tm = tid & 15, tn = tid >> 4;
    float c[4][4] = {};
    for (int k0 = 0; k0 < K_DIM; k0 += 16) {
        __syncthreads();
#pragma unroll
        for (int i = 0; i < 4; ++i) {
            int e = i * 256 + tid;
            As2[e >> 6][e & 63] = W[(size_t)(k0 + (e >> 6)) * M_DIM + bm * 64 + (e & 63)];
        }
#pragma unroll
        for (int i = 0; i < 4; ++i) {
            int e = i * 256 + tid;
            Bs2[e & 15][e >> 4] = X[(size_t)(bn * 64 + (e >> 4)) * K_DIM + k0 + (e & 15)];
        }
        __syncthreads();
#pragma unroll
        for (int kk = 0; kk < 16; ++kk)
#pragma unroll
            for (int i = 0; i < 4; ++i)
#pragma unroll
                for (int j = 0; j < 4; ++j)
                    c[i][j] += As2[kk][tm * 4 + i] * Bs2[kk][tn * 4 + j];
    }
#pragma unroll
    for (int i = 0; i < 4; ++i)
#pragma unroll
        for (int j = 0; j < 4; ++j)
            C[(size_t)(bm * 64 + tm * 4 + i) * N_DIM + bn * 64 + tn * 4 + j] = c[i][j];
}

// ---------------- launch ----------------

extern "C" void kernel_launch(void* const* d_in, const int* in_sizes, int n_in,
                              void* d_out, int out_size, void* d_ws, size_t ws_size,
                              hipStream_t stream) {
    const float* X = (const float*)d_in[0];  // [8192, 2048]
    const float* W = (const float*)d_in[1];  // [2048, 2048]
    // d_in[2] = bias: intentionally unused (reference discards it)
    float* C = (float*)d_out;                // [2048, 8192]

    const size_t xb_bytes = (size_t)N_DIM * K_DIM * sizeof(_Float16);  // 32 MB
    const size_t wt_bytes = (size_t)M_DIM * K_DIM * sizeof(_Float16);  //  8 MB

    if (ws_size >= xb_bytes + wt_bytes + 64) {
        static bool attr_set = false;
        if (!attr_set) {
            (void)hipFuncSetAttribute(reinterpret_cast<const void*>(fused_gemm),
                                      hipFuncAttributeMaxDynamicSharedMemorySize,
                                      131072);
            attr_set = true;
        }
        _Float16* Xb = (_Float16*)d_ws;
        _Float16* Wt = (_Float16*)((char*)d_ws + xb_bytes);
        unsigned* cnt = (unsigned*)((char*)d_ws + xb_bytes + wt_bytes);
        hipMemsetAsync(cnt, 0, sizeof(unsigned), stream);
        fused_gemm<<<256, 512, 131072, stream>>>(X, W, Xb, Wt, cnt, C);
    } else {
        gemm_f32_fallback<<<(M_DIM / 64) * (N_DIM / 64), 256, 0, stream>>>(X, W, C);
    }
}